// Round 3
// baseline (176.770 us; speedup 1.0000x reference)
//
#include <hip/hip_runtime.h>
#include <hip/hip_cooperative_groups.h>

namespace cg = cooperative_groups;

// LambdaRankLoss: B=64, N=1024, binary relevances, SIGMA=1, NDCG@10, EPS=1e-8.
// loss = (1/num_pairs) * sum_{valid b} sum_{i in rel, j in nonrel}
//            |disc_i - disc_j| / (idcg_b + eps) * softplus(s_j - s_i)
// valid b  <=>  0 < nrel_b < N ; idcg_b = sum_{p < min(nrel_b,10)} 1/log2(p+2)
//
// Round 13 = Round 10 (66.7 us baseline) made SINGLE-LAUNCH via cooperative
// grid sync. R11/R12 post-mortem: an in-stream init node for atomic counters
// costs more than the lr_final kernel it replaces (R12's 524-B D2D memcpy =
// SDMA engine, ~5-6 us with cross-engine semaphores -> 68.5 us net WORSE).
// The cooperative grid barrier's state is runtime-owned — the harness's
// workspace re-poison cannot touch it — so it needs NO init node at all:
//   - pair phase: byte-identical staging + hot loop vs R10 (absmax 0.0)
//   - each block plain-stores its partial (own slot), slice 0 stores pairCnt
//   - __threadfence() + grid.sync()  (agent-scope release + arrival barrier)
//   - block 0 runs the old lr_final body in-place, writes out[0]
// Fixed-order reductions everywhere -> bitwise deterministic.
// Co-residency: 1024 blocks x 256 thr; ~8.9 KB LDS -> 4 blocks/CU (35.5 KB
// of 160 KB); __launch_bounds__(256,4) caps VGPR<=128 so 16 waves/CU fit.

#define NPOS   1024
#define SPLIT  16                      // slices per batch; grid = B*SPLIT
#define KTOP   10
#define EPSF   1e-8f
#define MAXSL  ((NPOS + SPLIT - 1) / SPLIT)   // 64 rel items per slice max
#define MAXB   64
#define LOG2E  1.4426950408889634f
#define LN2    0.6931471805599453

// prefix sums of 1/log2(p+2), p=0..9: idcg = IDCG_S[min(nrel,10)]
__device__ const float IDCG_S[11] = {
    0.0f, 1.0f, 1.63092975f, 2.13092975f, 2.56160631f, 2.94845912f,
    3.30466631f, 3.63799964f, 3.95346452f, 4.25449452f, 4.54355935f
};

// softplus(z)/ln2 with z' = z*log2e:  max(z',0) + log1p(exp2(-|z'|))/ln2
// cubic fit of log1p(t)/t on (0,1], coeffs pre-divided by ln2 (abs err ~5e-4)
__device__ __forceinline__ float softplus_log2(float zp) {
    const float t = __builtin_amdgcn_exp2f(-fabsf(zp));   // v_exp, -abs folded
    const float g = t * (1.442216f + t * (-0.701718f
                  + t * (0.365639f + t * (-0.106478f))));
    return fmaxf(zp, 0.0f) + g;
}

__device__ __forceinline__ float inv_log2_f(float x) {
    return __builtin_amdgcn_rcpf(__log2f(x));   // ~1e-5 rel err, fine
}

__global__ __launch_bounds__(256, 4) void lr_fused_kernel(
    const float* __restrict__ scores,
    const int*   __restrict__ relev,
    double*      __restrict__ partials,   // one slot per block
    unsigned*    __restrict__ pairCnt,    // one slot per batch (slice 0 writes)
    float*       __restrict__ out,
    int B, int nparts)
{
    __shared__ __align__(16) float2 nshr[NPOS];  // nonrel (score*log2e, disc)
    __shared__ float2 rshr[MAXSL];       // this slice's rel items only
    __shared__ int    cnt[16];           // rel count per 64-item chunk
    __shared__ double wsum[4];
    __shared__ long long psh[4];         // block-0 final reduce only

    const int b     = blockIdx.x >> 4;           // SPLIT == 16
    const int slice = blockIdx.x & (SPLIT - 1);
    const int tid   = threadIdx.x;
    const int lane  = tid & 63;
    const int wave  = tid >> 6;

    const float* srow = scores + (size_t)b * NPOS;
    const int*   rrow = relev  + (size_t)b * NPOS;

    // ---- Phase 1: load + per-chunk ballot counts (chunk c -> wave c&3) ----
    float sv[4], dv[4]; int rposv[4]; bool rf[4];
    #pragma unroll
    for (int it = 0; it < 4; ++it) {
        const int c = it * 4 + wave, idx = c * 64 + lane;
        sv[it] = srow[idx] * LOG2E;              // pre-scale into log2-units
        dv[it] = inv_log2_f((float)idx + 2.0f);
        const bool r = rrow[idx] > 0; rf[it] = r;
        unsigned long long m = __ballot(r);
        rposv[it] = __popcll(m & ((1ull << lane) - 1ull));
        if (lane == 0) cnt[c] = __popcll(m);
    }
    __syncthreads();

    int nrel = 0;
    #pragma unroll
    for (int c = 0; c < 16; ++c) nrel += cnt[c];  // uniform LDS broadcasts
    const int nnon = NPOS - nrel;
    const int i0 = (slice * nrel) / SPLIT;
    const int i1 = ((slice + 1) * nrel) / SPLIT;
    const int ni = i1 - i0;

    // ---- Phase 2: deterministic stable scatter, incremental prefix scan ----
    {
        int rb = 0;                                   // sum cnt[0 .. c-1]
        for (int cc = 0; cc < wave; ++cc) rb += cnt[cc];
        #pragma unroll
        for (int it = 0; it < 4; ++it) {
            const int c = it * 4 + wave;
            if (rf[it]) {
                const int p = rb + rposv[it];
                if (p >= i0 && p < i1) rshr[p - i0] = make_float2(sv[it], dv[it]);
            } else {
                nshr[c * 64 - rb + (lane - rposv[it])] = make_float2(sv[it], dv[it]);
            }
            if (it < 3) rb += cnt[c] + cnt[c+1] + cnt[c+2] + cnt[c+3];
        }
    }

    const float idcg = IDCG_S[min(nrel, KTOP)];   // uniform table load
    __syncthreads();

    double block_total = 0.0;
    if (nrel > 0 && nnon > 0 && ni > 0) {        // block-uniform condition
        const float4* nshr4 = reinterpret_cast<const float4*>(nshr);
        const int nnon2 = nnon >> 1;

        // 4 independent accumulators; fixed order -> deterministic
        float acc0 = 0.f, acc1 = 0.f, acc2 = 0.f, acc3 = 0.f;
        int i = 0;
        for (; i + 4 <= ni; i += 4) {
            const float2 a0 = rshr[i], a1 = rshr[i+1], a2 = rshr[i+2], a3 = rshr[i+3];
            for (int jj = tid; jj < nnon2; jj += 256) {
                const float4 q = nshr4[jj];      // 2 items per ds_read_b128
                acc0 += fabsf(a0.y - q.y) * softplus_log2(q.x - a0.x);
                acc1 += fabsf(a1.y - q.y) * softplus_log2(q.x - a1.x);
                acc2 += fabsf(a2.y - q.y) * softplus_log2(q.x - a2.x);
                acc3 += fabsf(a3.y - q.y) * softplus_log2(q.x - a3.x);
                acc0 += fabsf(a0.y - q.w) * softplus_log2(q.z - a0.x);
                acc1 += fabsf(a1.y - q.w) * softplus_log2(q.z - a1.x);
                acc2 += fabsf(a2.y - q.w) * softplus_log2(q.z - a2.x);
                acc3 += fabsf(a3.y - q.w) * softplus_log2(q.z - a3.x);
            }
        }
        for (; i < ni; ++i) {
            const float2 a0 = rshr[i];
            for (int jj = tid; jj < nnon2; jj += 256) {
                const float4 q = nshr4[jj];
                acc0 += fabsf(a0.y - q.y) * softplus_log2(q.x - a0.x);
                acc1 += fabsf(a0.y - q.w) * softplus_log2(q.z - a0.x);
            }
        }
        if (nnon & 1) {                          // odd tail: one pair/thread
            const float2 bj = nshr[nnon - 1];
            if (tid < ni) {
                const float2 a = rshr[tid];
                acc0 += fabsf(a.y - bj.y) * softplus_log2(bj.x - a.x);
            }
        }
        float acc = (acc0 + acc1) + (acc2 + acc3);

        // fixed-order wave shuffle reduce -> cross-wave LDS in double
        #pragma unroll
        for (int off = 32; off >= 1; off >>= 1) acc += __shfl_down(acc, off);
        if (lane == 0) wsum[wave] = (double)acc;
        __syncthreads();
        if (tid == 0)
            block_total = (wsum[0] + wsum[1] + wsum[2] + wsum[3])
                        * ((double)(1.0f / (idcg + EPSF)) * LN2);
    }

    // ---- per-block partial store (own slot, plain store) ----
    if (tid == 0) {
        partials[blockIdx.x] = block_total;
        if (slice == 0)
            pairCnt[b] = (nrel > 0 && nnon > 0) ? (unsigned)(nrel * nnon) : 0u;
    }
    __threadfence();                 // agent-scope release of the stores
    cg::this_grid().sync();          // runtime-owned barrier: no ws init needed

    // ---- block 0: the old lr_final body, in-place ----
    if (blockIdx.x == 0) {
        double tot = 0.0;
        for (int k = tid; k < nparts; k += 256) tot += partials[k];
        long long pairs = (tid < B) ? (long long)pairCnt[tid] : 0;

        #pragma unroll
        for (int off = 32; off >= 1; off >>= 1) {
            tot   += __shfl_down(tot, off);
            pairs += __shfl_down(pairs, off);
        }
        if (lane == 0) { wsum[wave] = tot; psh[wave] = pairs; }
        __syncthreads();
        if (tid == 0) {
            double    tt = wsum[0] + wsum[1] + wsum[2] + wsum[3];
            long long np = psh[0] + psh[1] + psh[2] + psh[3];
            out[0] = (np > 0) ? (float)(tt / (double)np) : 0.0f;
        }
    }
}

extern "C" void kernel_launch(void* const* d_in, const int* in_sizes, int n_in,
                              void* d_out, int out_size, void* d_ws, size_t ws_size,
                              hipStream_t stream) {
    const float* scores = (const float*)d_in[0];
    const int*   relev  = (const int*)d_in[1];
    float*       out    = (float*)d_out;
    int          B      = in_sizes[0] / NPOS;   // 64
    int          nparts = B * SPLIT;            // 1024

    double*   partials = (double*)d_ws;                    // nparts doubles
    unsigned* pairCnt  = (unsigned*)(partials + nparts);   // B uints
    // every read slot is written this call before use: no init node needed

    void* args[] = { (void*)&scores, (void*)&relev, (void*)&partials,
                     (void*)&pairCnt, (void*)&out, (void*)&B, (void*)&nparts };
    hipLaunchCooperativeKernel((const void*)lr_fused_kernel,
                               dim3(nparts), dim3(256), args, 0, stream);
}

// Round 4
// 66.880 us; speedup vs baseline: 2.6431x; 2.6431x over previous
//
#include <hip/hip_runtime.h>

// LambdaRankLoss: B=64, N=1024, binary relevances, SIGMA=1, NDCG@10, EPS=1e-8.
// loss = (1/num_pairs) * sum_{valid b} sum_{i in rel, j in nonrel}
//            |disc_i - disc_j| / (idcg_b + eps) * softplus(s_j - s_i)
// valid b  <=>  0 < nrel_b < N ; idcg_b = sum_{p < min(nrel_b,10)} 1/log2(p+2)
//
// Round 14: single kernel, ZERO init nodes.
//  - R11/R12 lesson: any in-stream init node (memset/memcpy) costs more than
//    the lr_final kernel it replaces (R12: 524-B D2D memcpy ~6 us -> 68.5).
//  - R13 lesson: cooperative grid.sync costs ~90 us at 1024 blocks. Rejected.
//  - R14: atomic-tree counters live in MODULE __device__ GLOBALS — zero-init
//    at load, NOT part of the harness-poisoned workspace — and the protocol
//    is SELF-RESETTING: every run leaves all counters at 0 for the next
//    (incl. rocprof replays). No workspace use at all.
// Tail protocol (bitwise deterministic — integer adds are order-free):
//  - block partial (double) -> 2^28 fixed-point u64 (deterministic per block)
//  - relaxed packed atomicAdd into g_batch[b] ([63:53] arrivals, [52:0] sum);
//    16th arriver captures batch sum from RMW return, resets g_batch[b]=0
//    (safe: all 16 arrived; same-location ordering on own ops)
//  - batch-last adds nrel*nnon to g_pairs (relaxed), then ACQ_REL packed add
//    into g_glob ([63:57] arrivals). Release publishes the pairs-add; the
//    64th's acquire (RMW release-sequence) sees all of them.
//  - 64th batch-finisher: full sum in RMW return; resets g_glob=0, drains
//    g_pairs via atomicExch(0) (ordered after the acquire), writes out[0].
// Fixed-point truncation ~1e-11 relative -> same float output bits.
// Hot loop + staging numerics byte-identical to the 66.7 us baseline.

#define NPOS   1024
#define SPLIT  16                      // slices per batch; grid = B*SPLIT
#define KTOP   10
#define EPSF   1e-8f
#define MAXSL  ((NPOS + SPLIT - 1) / SPLIT)   // 64 rel items per slice max
#define MAXB   64
#define LOG2E  1.4426950408889634f
#define LN2    0.6931471805599453
#define FPSCALE 268435456.0            // 2^28 fixed-point scale
#define BCNT_SHIFT 53                  // g_batch arrival-count field
#define GCNT_SHIFT 57                  // g_glob arrival-count field

// self-resetting atomic counters: module globals, zero-init at load,
// invariant "all zero at kernel entry" maintained by every run
__device__ unsigned long long g_batch[MAXB] = {};
__device__ unsigned long long g_glob = 0ull;
__device__ unsigned           g_pairs = 0u;

// prefix sums of 1/log2(p+2), p=0..9: idcg = IDCG_S[min(nrel,10)]
__device__ const float IDCG_S[11] = {
    0.0f, 1.0f, 1.63092975f, 2.13092975f, 2.56160631f, 2.94845912f,
    3.30466631f, 3.63799964f, 3.95346452f, 4.25449452f, 4.54355935f
};

// softplus(z)/ln2 with z' = z*log2e:  max(z',0) + log1p(exp2(-|z'|))/ln2
// cubic fit of log1p(t)/t on (0,1], coeffs pre-divided by ln2 (abs err ~5e-4)
__device__ __forceinline__ float softplus_log2(float zp) {
    const float t = __builtin_amdgcn_exp2f(-fabsf(zp));   // v_exp, -abs folded
    const float g = t * (1.442216f + t * (-0.701718f
                  + t * (0.365639f + t * (-0.106478f))));
    return fmaxf(zp, 0.0f) + g;
}

__device__ __forceinline__ float inv_log2_f(float x) {
    return __builtin_amdgcn_rcpf(__log2f(x));   // ~1e-5 rel err, fine
}

__global__ __launch_bounds__(256) void lr_pair_kernel(
    const float* __restrict__ scores,
    const int*   __restrict__ relev,
    float*       __restrict__ out)
{
    __shared__ __align__(16) float2 nshr[NPOS];  // nonrel (score*log2e, disc)
    __shared__ float2 rshr[MAXSL];       // this slice's rel items only
    __shared__ int    cnt[16];           // rel count per 64-item chunk
    __shared__ double wsum[4];

    const int b     = blockIdx.x >> 4;           // SPLIT == 16
    const int slice = blockIdx.x & (SPLIT - 1);
    const int tid   = threadIdx.x;
    const int lane  = tid & 63;
    const int wave  = tid >> 6;

    const float* srow = scores + (size_t)b * NPOS;
    const int*   rrow = relev  + (size_t)b * NPOS;

    // ---- Phase 1: load + per-chunk ballot counts (chunk c -> wave c&3) ----
    float sv[4], dv[4]; int rposv[4]; bool rf[4];
    #pragma unroll
    for (int it = 0; it < 4; ++it) {
        const int c = it * 4 + wave, idx = c * 64 + lane;
        sv[it] = srow[idx] * LOG2E;              // pre-scale into log2-units
        dv[it] = inv_log2_f((float)idx + 2.0f);
        const bool r = rrow[idx] > 0; rf[it] = r;
        unsigned long long m = __ballot(r);
        rposv[it] = __popcll(m & ((1ull << lane) - 1ull));
        if (lane == 0) cnt[c] = __popcll(m);
    }
    __syncthreads();

    int nrel = 0;
    #pragma unroll
    for (int c = 0; c < 16; ++c) nrel += cnt[c];  // uniform LDS broadcasts
    const int nnon = NPOS - nrel;
    const int i0 = (slice * nrel) / SPLIT;
    const int i1 = ((slice + 1) * nrel) / SPLIT;
    const int ni = i1 - i0;

    // ---- Phase 2: deterministic stable scatter, incremental prefix scan ----
    {
        int rb = 0;                                   // sum cnt[0 .. c-1]
        for (int cc = 0; cc < wave; ++cc) rb += cnt[cc];
        #pragma unroll
        for (int it = 0; it < 4; ++it) {
            const int c = it * 4 + wave;
            if (rf[it]) {
                const int p = rb + rposv[it];
                if (p >= i0 && p < i1) rshr[p - i0] = make_float2(sv[it], dv[it]);
            } else {
                nshr[c * 64 - rb + (lane - rposv[it])] = make_float2(sv[it], dv[it]);
            }
            if (it < 3) rb += cnt[c] + cnt[c+1] + cnt[c+2] + cnt[c+3];
        }
    }

    const float idcg = IDCG_S[min(nrel, KTOP)];   // uniform table load
    __syncthreads();

    double block_total = 0.0;
    if (nrel > 0 && nnon > 0 && ni > 0) {        // block-uniform condition
        const float4* nshr4 = reinterpret_cast<const float4*>(nshr);
        const int nnon2 = nnon >> 1;

        // 4 independent accumulators; fixed order -> deterministic
        float acc0 = 0.f, acc1 = 0.f, acc2 = 0.f, acc3 = 0.f;
        int i = 0;
        for (; i + 4 <= ni; i += 4) {
            const float2 a0 = rshr[i], a1 = rshr[i+1], a2 = rshr[i+2], a3 = rshr[i+3];
            for (int jj = tid; jj < nnon2; jj += 256) {
                const float4 q = nshr4[jj];      // 2 items per ds_read_b128
                acc0 += fabsf(a0.y - q.y) * softplus_log2(q.x - a0.x);
                acc1 += fabsf(a1.y - q.y) * softplus_log2(q.x - a1.x);
                acc2 += fabsf(a2.y - q.y) * softplus_log2(q.x - a2.x);
                acc3 += fabsf(a3.y - q.y) * softplus_log2(q.x - a3.x);
                acc0 += fabsf(a0.y - q.w) * softplus_log2(q.z - a0.x);
                acc1 += fabsf(a1.y - q.w) * softplus_log2(q.z - a1.x);
                acc2 += fabsf(a2.y - q.w) * softplus_log2(q.z - a2.x);
                acc3 += fabsf(a3.y - q.w) * softplus_log2(q.z - a3.x);
            }
        }
        for (; i < ni; ++i) {
            const float2 a0 = rshr[i];
            for (int jj = tid; jj < nnon2; jj += 256) {
                const float4 q = nshr4[jj];
                acc0 += fabsf(a0.y - q.y) * softplus_log2(q.x - a0.x);
                acc1 += fabsf(a0.y - q.w) * softplus_log2(q.z - a0.x);
            }
        }
        if (nnon & 1) {                          // odd tail: one pair/thread
            const float2 bj = nshr[nnon - 1];
            if (tid < ni) {
                const float2 a = rshr[tid];
                acc0 += fabsf(a.y - bj.y) * softplus_log2(bj.x - a.x);
            }
        }
        float acc = (acc0 + acc1) + (acc2 + acc3);

        // fixed-order wave shuffle reduce -> cross-wave LDS in double
        #pragma unroll
        for (int off = 32; off >= 1; off >>= 1) acc += __shfl_down(acc, off);
        if (lane == 0) wsum[wave] = (double)acc;
        __syncthreads();
        if (tid == 0)
            block_total = (wsum[0] + wsum[1] + wsum[2] + wsum[3])
                        * ((double)(1.0f / (idcg + EPSF)) * LN2);
    }

    // ---- Tail: self-resetting two-level integer-atomic reduction ----
    if (tid == 0) {
        const unsigned long long fp =
            (unsigned long long)(block_total * FPSCALE + 0.5);
        const unsigned long long old =
            atomicAdd(&g_batch[b], (1ull << BCNT_SHIFT) | fp);    // relaxed
        if ((old >> BCNT_SHIFT) == SPLIT - 1) {
            // 16th arriver: all of batch b is in; reset for next run
            __hip_atomic_store(&g_batch[b], 0ull,
                               __ATOMIC_RELAXED, __HIP_MEMORY_SCOPE_AGENT);
            const unsigned long long bfp =
                (old & ((1ull << BCNT_SHIFT) - 1)) + fp;
            if (nrel > 0 && nnon > 0)
                atomicAdd(&g_pairs, (unsigned)(nrel * nnon));     // relaxed
            // acq_rel: releases the pairs-add; acquires all prior batch-lasts'
            // releases via the RMW release-sequence on g_glob
            const unsigned long long g = __hip_atomic_fetch_add(
                &g_glob, (1ull << GCNT_SHIFT) | bfp,
                __ATOMIC_ACQ_REL, __HIP_MEMORY_SCOPE_AGENT);
            if ((g >> GCNT_SHIFT) == MAXB - 1) {
                // 64th batch-finisher: full sum in hand; reset + drain
                __hip_atomic_store(&g_glob, 0ull,
                                   __ATOMIC_RELAXED, __HIP_MEMORY_SCOPE_AGENT);
                const unsigned np = atomicExch(&g_pairs, 0u);
                const double tot =
                    (double)((g & ((1ull << GCNT_SHIFT) - 1)) + fp
                             + (old & ((1ull << BCNT_SHIFT) - 1)))
                    * (1.0 / FPSCALE);
                out[0] = (np > 0) ? (float)(tot / (double)np) : 0.0f;
            }
        }
    }
}

extern "C" void kernel_launch(void* const* d_in, const int* in_sizes, int n_in,
                              void* d_out, int out_size, void* d_ws, size_t ws_size,
                              hipStream_t stream) {
    const float* scores = (const float*)d_in[0];
    const int*   relev  = (const int*)d_in[1];
    float*       out    = (float*)d_out;
    const int    B      = in_sizes[0] / NPOS;   // 64
    const int    nparts = B * SPLIT;            // 1024

    // no workspace use, no init node: counters are self-resetting module
    // globals — one kernel node is the entire graph contribution
    lr_pair_kernel<<<nparts, 256, 0, stream>>>(scores, relev, out);
}

// Round 5
// 65.720 us; speedup vs baseline: 2.6898x; 1.0177x over previous
//
#include <hip/hip_runtime.h>

// LambdaRankLoss: B=64, N=1024, binary relevances, SIGMA=1, NDCG@10, EPS=1e-8.
// loss = (1/num_pairs) * sum_{valid b} sum_{i in rel, j in nonrel}
//            |disc_i - disc_j| / (idcg_b + eps) * softplus(s_j - s_i)
// valid b  <=>  0 < nrel_b < N ; idcg_b = sum_{p < min(nrel_b,10)} 1/log2(p+2)
//
// Round 15 = Round 14 (66.88 us, single kernel, self-resetting atomic tail)
// with the HOT LOOP rewritten for packed f32 math + register-resident q:
//  - R14 lesson: orchestration is exhausted (removing a whole kernel node
//    changed nothing). The only controllable time left is pair-kernel exec.
//  - Packed v_pk_{add,mul,fma,max}_f32 (VOP3P) over the two nonrel items of
//    each float4: ~28 cyc/2 pairs vs ~44 scalar (exp2 stays scalar x2;
//    abs via pk_max(x,-x) since VOP3P has no abs modifier).
//  - Each thread's q (<= 2 float4s, since nnon2 <= 511) is loaded from LDS
//    ONCE into registers; the hot loop has ZERO ds_read (was 8 ds_read_b128
//    + lgkmcnt stalls per thread).
//  - Same coefficients, same per-element ops; only accumulation order
//    changes (packed lanes combined at end) -> output may move ~1 ulp.
// Tail: self-resetting two-level integer-atomic reduction in module globals
// (zero-init at load, invariant "all zero at entry" maintained every run,
// incl. rocprof replays). Integer adds order-free -> deterministic.

#define NPOS   1024
#define SPLIT  16                      // slices per batch; grid = B*SPLIT
#define KTOP   10
#define EPSF   1e-8f
#define MAXSL  ((NPOS + SPLIT - 1) / SPLIT)   // 64 rel items per slice max
#define MAXB   64
#define LOG2E  1.4426950408889634f
#define LN2    0.6931471805599453
#define FPSCALE 268435456.0            // 2^28 fixed-point scale
#define BCNT_SHIFT 53                  // g_batch arrival-count field
#define GCNT_SHIFT 57                  // g_glob arrival-count field

typedef float f32x2 __attribute__((ext_vector_type(2)));

// self-resetting atomic counters: module globals, zero-init at load
__device__ unsigned long long g_batch[MAXB] = {};
__device__ unsigned long long g_glob = 0ull;
__device__ unsigned           g_pairs = 0u;

// prefix sums of 1/log2(p+2), p=0..9: idcg = IDCG_S[min(nrel,10)]
__device__ const float IDCG_S[11] = {
    0.0f, 1.0f, 1.63092975f, 2.13092975f, 2.56160631f, 2.94845912f,
    3.30466631f, 3.63799964f, 3.95346452f, 4.25449452f, 4.54355935f
};

// packed softplus(z)/ln2, z in log2-units: max(z,0) + log1p(exp2(-|z|))/ln2
// cubic fit of log1p(t)/t on (0,1], coeffs pre-divided by ln2 (abs err ~5e-4)
__device__ __forceinline__ f32x2 sp2_log2(f32x2 z) {
    f32x2 t;
    t.x = __builtin_amdgcn_exp2f(-fabsf(z.x));   // v_exp, -|.| folds (VOP1)
    t.y = __builtin_amdgcn_exp2f(-fabsf(z.y));
    const f32x2 g = t * (1.442216f + t * (-0.701718f
                   + t * (0.365639f + t * (-0.106478f))));   // 4x v_pk_fma
    return __builtin_elementwise_max(z, (f32x2)(0.0f)) + g;  // pk_max+pk_add
}

// two pairs (one rel item a vs two nonrel items in qx/qy) -> packed acc
__device__ __forceinline__ void pair2(const float2 a, const f32x2 qx,
                                      const f32x2 qy, f32x2& accv) {
    const f32x2 z  = qx - (f32x2)(a.x);          // pk_add (neg mod)
    const f32x2 sp = sp2_log2(z);
    const f32x2 dy = (f32x2)(a.y) - qy;          // pk_add (neg mod)
    const f32x2 ad = __builtin_elementwise_max(dy, -dy);   // pk_max (|dy|)
    accv += ad * sp;                             // pk_fma
}

// scalar softplus for the odd-nnon tail (same coeffs)
__device__ __forceinline__ float softplus_log2(float zp) {
    const float t = __builtin_amdgcn_exp2f(-fabsf(zp));
    const float g = t * (1.442216f + t * (-0.701718f
                  + t * (0.365639f + t * (-0.106478f))));
    return fmaxf(zp, 0.0f) + g;
}

__device__ __forceinline__ float inv_log2_f(float x) {
    return __builtin_amdgcn_rcpf(__log2f(x));   // ~1e-5 rel err, fine
}

__global__ __launch_bounds__(256) void lr_pair_kernel(
    const float* __restrict__ scores,
    const int*   __restrict__ relev,
    float*       __restrict__ out)
{
    __shared__ __align__(16) float2 nshr[NPOS];  // nonrel (score*log2e, disc)
    __shared__ float2 rshr[MAXSL];       // this slice's rel items only
    __shared__ int    cnt[16];           // rel count per 64-item chunk
    __shared__ double wsum[4];

    const int b     = blockIdx.x >> 4;           // SPLIT == 16
    const int slice = blockIdx.x & (SPLIT - 1);
    const int tid   = threadIdx.x;
    const int lane  = tid & 63;
    const int wave  = tid >> 6;

    const float* srow = scores + (size_t)b * NPOS;
    const int*   rrow = relev  + (size_t)b * NPOS;

    // ---- Phase 1: load + per-chunk ballot counts (chunk c -> wave c&3) ----
    float sv[4], dv[4]; int rposv[4]; bool rf[4];
    #pragma unroll
    for (int it = 0; it < 4; ++it) {
        const int c = it * 4 + wave, idx = c * 64 + lane;
        sv[it] = srow[idx] * LOG2E;              // pre-scale into log2-units
        dv[it] = inv_log2_f((float)idx + 2.0f);
        const bool r = rrow[idx] > 0; rf[it] = r;
        unsigned long long m = __ballot(r);
        rposv[it] = __popcll(m & ((1ull << lane) - 1ull));
        if (lane == 0) cnt[c] = __popcll(m);
    }
    __syncthreads();

    int nrel = 0;
    #pragma unroll
    for (int c = 0; c < 16; ++c) nrel += cnt[c];  // uniform LDS broadcasts
    const int nnon = NPOS - nrel;
    const int i0 = (slice * nrel) / SPLIT;
    const int i1 = ((slice + 1) * nrel) / SPLIT;
    const int ni = i1 - i0;

    // ---- Phase 2: deterministic stable scatter, incremental prefix scan ----
    {
        int rb = 0;                                   // sum cnt[0 .. c-1]
        for (int cc = 0; cc < wave; ++cc) rb += cnt[cc];
        #pragma unroll
        for (int it = 0; it < 4; ++it) {
            const int c = it * 4 + wave;
            if (rf[it]) {
                const int p = rb + rposv[it];
                if (p >= i0 && p < i1) rshr[p - i0] = make_float2(sv[it], dv[it]);
            } else {
                nshr[c * 64 - rb + (lane - rposv[it])] = make_float2(sv[it], dv[it]);
            }
            if (it < 3) rb += cnt[c] + cnt[c+1] + cnt[c+2] + cnt[c+3];
        }
    }

    const float idcg = IDCG_S[min(nrel, KTOP)];   // uniform table load
    __syncthreads();

    double block_total = 0.0;
    if (nrel > 0 && nnon > 0 && ni > 0) {        // block-uniform condition
        const float4* nshr4 = reinterpret_cast<const float4*>(nshr);
        const int nnon2 = nnon >> 1;             // <= 511 (nrel >= 1)

        // this thread's nonrel items -> REGISTERS, read from LDS exactly once
        const bool has0 = tid < nnon2;
        const bool has1 = tid + 256 < nnon2;
        float4 q0 = has0 ? nshr4[tid]       : make_float4(0.f, 0.f, 0.f, 0.f);
        float4 q1 = has1 ? nshr4[tid + 256] : make_float4(0.f, 0.f, 0.f, 0.f);
        const f32x2 q0x = {q0.x, q0.z}, q0y = {q0.y, q0.w};
        const f32x2 q1x = {q1.x, q1.z}, q1y = {q1.y, q1.w};

        // 4 packed accumulators; fixed per-thread order -> deterministic
        f32x2 acc0v = (f32x2)(0.f), acc1v = (f32x2)(0.f);
        f32x2 acc2v = (f32x2)(0.f), acc3v = (f32x2)(0.f);
        float tailacc = 0.f;

        int i = 0;
        for (; i + 4 <= ni; i += 4) {
            const float2 a0 = rshr[i],   a1 = rshr[i+1];
            const float2 a2 = rshr[i+2], a3 = rshr[i+3];
            if (has0) {
                pair2(a0, q0x, q0y, acc0v);
                pair2(a1, q0x, q0y, acc1v);
                pair2(a2, q0x, q0y, acc2v);
                pair2(a3, q0x, q0y, acc3v);
            }
            if (has1) {
                pair2(a0, q1x, q1y, acc0v);
                pair2(a1, q1x, q1y, acc1v);
                pair2(a2, q1x, q1y, acc2v);
                pair2(a3, q1x, q1y, acc3v);
            }
        }
        for (; i < ni; ++i) {
            const float2 a0 = rshr[i];
            if (has0) pair2(a0, q0x, q0y, acc0v);
            if (has1) pair2(a0, q1x, q1y, acc1v);
        }
        if (nnon & 1) {                          // odd tail: one pair/thread
            const float2 bj = nshr[nnon - 1];
            if (tid < ni) {
                const float2 a = rshr[tid];
                tailacc = fabsf(a.y - bj.y) * softplus_log2(bj.x - a.x);
            }
        }
        float acc = (((acc0v.x + acc0v.y) + (acc1v.x + acc1v.y))
                   + ((acc2v.x + acc2v.y) + (acc3v.x + acc3v.y))) + tailacc;

        // fixed-order wave shuffle reduce -> cross-wave LDS in double
        #pragma unroll
        for (int off = 32; off >= 1; off >>= 1) acc += __shfl_down(acc, off);
        if (lane == 0) wsum[wave] = (double)acc;
        __syncthreads();
        if (tid == 0)
            block_total = (wsum[0] + wsum[1] + wsum[2] + wsum[3])
                        * ((double)(1.0f / (idcg + EPSF)) * LN2);
    }

    // ---- Tail: self-resetting two-level integer-atomic reduction ----
    if (tid == 0) {
        const unsigned long long fp =
            (unsigned long long)(block_total * FPSCALE + 0.5);
        const unsigned long long old =
            atomicAdd(&g_batch[b], (1ull << BCNT_SHIFT) | fp);    // relaxed
        if ((old >> BCNT_SHIFT) == SPLIT - 1) {
            // 16th arriver: all of batch b is in; reset for next run
            __hip_atomic_store(&g_batch[b], 0ull,
                               __ATOMIC_RELAXED, __HIP_MEMORY_SCOPE_AGENT);
            const unsigned long long bfp =
                (old & ((1ull << BCNT_SHIFT) - 1)) + fp;
            if (nrel > 0 && nnon > 0)
                atomicAdd(&g_pairs, (unsigned)(nrel * nnon));     // relaxed
            // acq_rel: releases the pairs-add; acquires all prior batch-lasts'
            // releases via the RMW release-sequence on g_glob
            const unsigned long long g = __hip_atomic_fetch_add(
                &g_glob, (1ull << GCNT_SHIFT) | bfp,
                __ATOMIC_ACQ_REL, __HIP_MEMORY_SCOPE_AGENT);
            if ((g >> GCNT_SHIFT) == MAXB - 1) {
                // 64th batch-finisher: full sum in hand; reset + drain
                __hip_atomic_store(&g_glob, 0ull,
                                   __ATOMIC_RELAXED, __HIP_MEMORY_SCOPE_AGENT);
                const unsigned np = atomicExch(&g_pairs, 0u);
                const double tot =
                    (double)((g & ((1ull << GCNT_SHIFT) - 1)) + bfp)
                    * (1.0 / FPSCALE);
                out[0] = (np > 0) ? (float)(tot / (double)np) : 0.0f;
            }
        }
    }
}

extern "C" void kernel_launch(void* const* d_in, const int* in_sizes, int n_in,
                              void* d_out, int out_size, void* d_ws, size_t ws_size,
                              hipStream_t stream) {
    const float* scores = (const float*)d_in[0];
    const int*   relev  = (const int*)d_in[1];
    float*       out    = (float*)d_out;
    const int    B      = in_sizes[0] / NPOS;   // 64
    const int    nparts = B * SPLIT;            // 1024

    // no workspace use, no init node: counters are self-resetting module
    // globals — one kernel node is the entire graph contribution
    lr_pair_kernel<<<nparts, 256, 0, stream>>>(scores, relev, out);
}